// Round 1
// baseline (3241.629 us; speedup 1.0000x reference)
//
#include <hip/hip_runtime.h>

// ---------------------------------------------------------------------------
// RGAT 2-hop, N=100000, E=1600000, D=64, R=64.
// Key algebra: e = concat(emb[h],emb[t]) . (W @ rel_e[r])  -- precompute
// Wr[r] = W @ relation_emb[r] (R x 128) once; per edge it's two 64-dots.
// Softmax-agg folded: agg[h] = sum(ex * emb[t]);  emb' = emb + agg/denom.
// ---------------------------------------------------------------------------

#define NEG_SLOPE 0.2f

__device__ __forceinline__ unsigned f2ord(float f) {
    unsigned u = __float_as_uint(f);
    return (u & 0x80000000u) ? ~u : (u | 0x80000000u);
}
__device__ __forceinline__ float ord2f(unsigned o) {
    unsigned u = (o & 0x80000000u) ? (o ^ 0x80000000u) : ~o;
    return __uint_as_float(u);
}

// Wuv[r*128 + i] = sum_j W[i][j] * rel[r][j],  i in [0,128)
__global__ void proj_kernel(const float* __restrict__ W,
                            const float* __restrict__ rel,
                            float* __restrict__ Wuv) {
    int r = blockIdx.x;
    int i = threadIdx.x;  // 0..127
    __shared__ float rels[64];
    if (i < 64) rels[i] = rel[r * 64 + i];
    __syncthreads();
    float s = 0.f;
#pragma unroll
    for (int j = 0; j < 64; ++j) s += W[i * 64 + j] * rels[j];
    Wuv[r * 128 + i] = s;
}

// One 16-lane group per edge; lane sub handles float4 of D.
__global__ __launch_bounds__(256) void edge_logits(
    const int* __restrict__ head, const int* __restrict__ tail,
    const int* __restrict__ etype, const float* __restrict__ emb,
    const float* __restrict__ Wuv, float* __restrict__ ebuf,
    unsigned* __restrict__ segmax, int E) {
    int g = (blockIdx.x * 256 + threadIdx.x) >> 4;
    int sub = threadIdx.x & 15;
    if (g >= E) return;
    int h = head[g], t = tail[g], r = etype[g];
    const float4 eh = *(const float4*)(emb + (long)h * 64 + sub * 4);
    const float4 et = *(const float4*)(emb + (long)t * 64 + sub * 4);
    const float4 u  = *(const float4*)(Wuv + r * 128 + sub * 4);
    const float4 v  = *(const float4*)(Wuv + r * 128 + 64 + sub * 4);
    float p = eh.x * u.x + eh.y * u.y + eh.z * u.z + eh.w * u.w +
              et.x * v.x + et.y * v.y + et.z * v.z + et.w * v.w;
    p += __shfl_xor(p, 1);
    p += __shfl_xor(p, 2);
    p += __shfl_xor(p, 4);
    p += __shfl_xor(p, 8);
    if (sub == 0) {
        float le = p > 0.f ? p : NEG_SLOPE * p;
        ebuf[g] = le;
        atomicMax(segmax + h, f2ord(le));
    }
}

// One 16-lane group per edge; scatter ex*emb[tail] into agg[head].
__global__ __launch_bounds__(256) void edge_scatter(
    const int* __restrict__ head, const int* __restrict__ tail,
    const float* __restrict__ emb, const float* __restrict__ ebuf,
    const unsigned* __restrict__ segmax, float* __restrict__ denom,
    float* __restrict__ agg, int E) {
    int g = (blockIdx.x * 256 + threadIdx.x) >> 4;
    int sub = threadIdx.x & 15;
    if (g >= E) return;
    int h = head[g], t = tail[g];
    float ex = __expf(ebuf[g] - ord2f(segmax[h]));
    const float4 et = *(const float4*)(emb + (long)t * 64 + sub * 4);
    float* ap = agg + (long)h * 64 + sub * 4;
    atomicAdd(ap + 0, ex * et.x);
    atomicAdd(ap + 1, ex * et.y);
    atomicAdd(ap + 2, ex * et.z);
    atomicAdd(ap + 3, ex * et.w);
    if (sub == 0) atomicAdd(denom + h, ex);
}

// One wave (64 lanes) per node: emb' = normalize(emb + agg/denom),
// res_out = 0.5*res_prev + emb'.  res_prev/res_out may alias (no restrict).
__global__ __launch_bounds__(256) void node_update(
    const float* __restrict__ emb_in, const float* __restrict__ agg,
    const float* __restrict__ denom, const float* res_prev,
    float* emb_out, float* res_out, int N) {
    int t = blockIdx.x * 256 + threadIdx.x;
    int n = t >> 6;
    int d = t & 63;
    if (n >= N) return;
    long idx = (long)n * 64 + d;
    float val = emb_in[idx];
    float den = denom[n];
    if (den > 0.f) val += agg[idx] / den;
    float sq = val * val;
#pragma unroll
    for (int m = 1; m < 64; m <<= 1) sq += __shfl_xor(sq, m);
    float norm = sqrtf(sq);
    float nv = val / fmaxf(norm, 1e-12f);
    if (emb_out) emb_out[idx] = nv;
    res_out[idx] = 0.5f * res_prev[idx] + nv;
}

extern "C" void kernel_launch(void* const* d_in, const int* in_sizes, int n_in,
                              void* d_out, int out_size, void* d_ws, size_t ws_size,
                              hipStream_t stream) {
    const int*   edge_index = (const int*)d_in[0];   // [2, E]
    const int*   etype      = (const int*)d_in[1];   // [E]
    const float* ent        = (const float*)d_in[2]; // [N, 64]
    const float* rel        = (const float*)d_in[3]; // [R, 64]
    const float* W          = (const float*)d_in[4]; // [128, 64]

    const int E = in_sizes[1];
    const int N = in_sizes[2] / 64;
    const int R = in_sizes[3] / 64;
    const int* head = edge_index;
    const int* tail = edge_index + E;
    float* out = (float*)d_out;

    // workspace layout
    char* w = (char*)d_ws;
    float* Wuv = (float*)w;      w += (size_t)R * 128 * 4;
    float* ebuf = (float*)w;     w += (size_t)E * 4;
    unsigned* segmax = (unsigned*)w; w += (size_t)N * 4;
    float* denom = (float*)w;    w += (size_t)N * 4;
    float* agg = (float*)w;      w += (size_t)N * 64 * 4;
    float* emb1 = (float*)w;     w += (size_t)N * 64 * 4;

    proj_kernel<<<R, 128, 0, stream>>>(W, rel, Wuv);

    const int egrid = (E + 15) / 16;          // 16 edges per 256-thread block
    const int ngrid = (N * 64 + 255) / 256;   // 4 nodes per 256-thread block

    // ---- hop 1 (emb_in = ent, res_prev = ent) ----
    hipMemsetAsync(segmax, 0, (size_t)N * 4, stream);
    hipMemsetAsync(denom, 0, (size_t)N * 4, stream);
    hipMemsetAsync(agg, 0, (size_t)N * 64 * 4, stream);
    edge_logits<<<egrid, 256, 0, stream>>>(head, tail, etype, ent, Wuv, ebuf, segmax, E);
    edge_scatter<<<egrid, 256, 0, stream>>>(head, tail, ent, ebuf, segmax, denom, agg, E);
    node_update<<<ngrid, 256, 0, stream>>>(ent, agg, denom, ent, emb1, out, N);

    // ---- hop 2 (emb_in = emb1, res_prev = out, in-place res) ----
    hipMemsetAsync(segmax, 0, (size_t)N * 4, stream);
    hipMemsetAsync(denom, 0, (size_t)N * 4, stream);
    hipMemsetAsync(agg, 0, (size_t)N * 64 * 4, stream);
    edge_logits<<<egrid, 256, 0, stream>>>(head, tail, etype, emb1, Wuv, ebuf, segmax, E);
    edge_scatter<<<egrid, 256, 0, stream>>>(head, tail, emb1, ebuf, segmax, denom, agg, E);
    node_update<<<ngrid, 256, 0, stream>>>(emb1, agg, denom, out, nullptr, out, N);
}

// Round 2
// 1056.462 us; speedup vs baseline: 3.0684x; 3.0684x over previous
//
#include <hip/hip_runtime.h>

// ---------------------------------------------------------------------------
// RGAT 2-hop, N=100000, E=1600000, D=64, R=64.
// R2: atomic-free. Per-launch CSR build (hist/scan/fill), then one fully
// fused node-centric hop kernel: online softmax + aggregate + L2-normalize
// + residual, one wave per node (lane = dim), Wuv staged in LDS.
// e = emb[h].u[r] + emb[t].v[r] with Wuv[r] = W @ rel[r] precomputed.
// ---------------------------------------------------------------------------

#define NEG_SLOPE 0.2f

// Wuv[r*128 + i] = sum_j W[i][j] * rel[r][j],  i in [0,128)
__global__ void proj_kernel(const float* __restrict__ W,
                            const float* __restrict__ rel,
                            float* __restrict__ Wuv) {
    int r = blockIdx.x;
    int i = threadIdx.x;  // 0..127
    __shared__ float rels[64];
    if (i < 64) rels[i] = rel[r * 64 + i];
    __syncthreads();
    float s = 0.f;
#pragma unroll
    for (int j = 0; j < 64; ++j) s += W[i * 64 + j] * rels[j];
    Wuv[r * 128 + i] = s;
}

// ---------------- CSR build ----------------

__global__ __launch_bounds__(256) void hist_kernel(
    const int* __restrict__ head, int* __restrict__ deg, int E) {
    int i = blockIdx.x * 256 + threadIdx.x;
    if (i < E) atomicAdd(deg + head[i], 1);
}

__global__ __launch_bounds__(256) void block_sum_kernel(
    const int* __restrict__ deg, int* __restrict__ bsum, int N) {
    int i = blockIdx.x * 256 + threadIdx.x;
    int v = (i < N) ? deg[i] : 0;
#pragma unroll
    for (int m = 1; m < 64; m <<= 1) v += __shfl_xor(v, m);
    __shared__ int ws[4];
    if ((threadIdx.x & 63) == 0) ws[threadIdx.x >> 6] = v;
    __syncthreads();
    if (threadIdx.x == 0) bsum[blockIdx.x] = ws[0] + ws[1] + ws[2] + ws[3];
}

// single-block Hillis-Steele exclusive scan of bsum (nb <= 512)
__global__ __launch_bounds__(512) void scan_bsum_kernel(int* bsum, int nb) {
    __shared__ int s[512];
    int i = threadIdx.x;
    s[i] = (i < nb) ? bsum[i] : 0;
    __syncthreads();
    for (int off = 1; off < 512; off <<= 1) {
        int v = (i >= off) ? s[i - off] : 0;
        __syncthreads();
        s[i] += v;
        __syncthreads();
    }
    if (i < nb) bsum[i] = (i == 0) ? 0 : s[i - 1];
}

__global__ __launch_bounds__(256) void row_start_kernel(
    const int* __restrict__ deg, const int* __restrict__ bsum,
    int* __restrict__ rowstart, int* __restrict__ cursor, int N, int E) {
    int i = blockIdx.x * 256 + threadIdx.x;
    int v = (i < N) ? deg[i] : 0;
    int lane = threadIdx.x & 63;
    int wid = threadIdx.x >> 6;
    int sc = v;  // wave inclusive scan
#pragma unroll
    for (int off = 1; off < 64; off <<= 1) {
        int t = __shfl_up(sc, off);
        if (lane >= off) sc += t;
    }
    __shared__ int wsum[4];
    if (lane == 63) wsum[wid] = sc;
    __syncthreads();
    int wo = 0;
    for (int w = 0; w < wid; ++w) wo += wsum[w];
    int ex = sc - v + wo + bsum[blockIdx.x];
    if (i < N) { rowstart[i] = ex; cursor[i] = ex; }
    if (i == N - 1) rowstart[N] = E;
}

__global__ __launch_bounds__(256) void fill_kernel(
    const int* __restrict__ head, const int* __restrict__ tail,
    const int* __restrict__ etype, int* __restrict__ cursor,
    int* __restrict__ csr_tail, int* __restrict__ csr_rtype, int E) {
    int i = blockIdx.x * 256 + threadIdx.x;
    if (i >= E) return;
    int h = head[i];
    int pos = atomicAdd(cursor + h, 1);
    csr_tail[pos] = tail[i];
    csr_rtype[pos] = etype[i];
}

// ---------------- fused hop ----------------
// One wave per node (4 nodes / 256-thread block). Lane d owns dim d.
// Online softmax over the node's CSR row; fused normalize + residual.
__global__ __launch_bounds__(256) void hop_kernel(
    const int* __restrict__ rowstart, const int* __restrict__ csr_tail,
    const int* __restrict__ csr_rtype, const float* __restrict__ Wuv,
    const float* __restrict__ emb_in, const float* res_prev,
    float* emb_out, float* res_out, int N) {
    __shared__ float sWuv[64 * 128];  // 32 KB
    for (int i = threadIdx.x; i < 64 * 128; i += 256) sWuv[i] = Wuv[i];
    __syncthreads();

    int node = blockIdx.x * 4 + (threadIdx.x >> 6);
    int d = threadIdx.x & 63;
    if (node >= N) return;
    long base = (long)node * 64 + d;
    float hd = emb_in[base];
    int s0 = rowstart[node], s1 = rowstart[node + 1];
    float m = -1e30f, l = 0.f, agg = 0.f;
    for (int s = s0; s < s1; ++s) {
        int t = csr_tail[s];
        int r = csr_rtype[s];
        float td = emb_in[(long)t * 64 + d];
        float p = hd * sWuv[r * 128 + d] + td * sWuv[r * 128 + 64 + d];
        p += __shfl_xor(p, 1);  p += __shfl_xor(p, 2);
        p += __shfl_xor(p, 4);  p += __shfl_xor(p, 8);
        p += __shfl_xor(p, 16); p += __shfl_xor(p, 32);
        float e = p > 0.f ? p : NEG_SLOPE * p;
        float nm = fmaxf(m, e);
        float scale = __expf(m - nm);
        float w = __expf(e - nm);
        l = l * scale + w;
        agg = agg * scale + w * td;
        m = nm;
    }
    float val = hd;
    if (l > 0.f) val += agg / l;
    float sq = val * val;
    sq += __shfl_xor(sq, 1);  sq += __shfl_xor(sq, 2);
    sq += __shfl_xor(sq, 4);  sq += __shfl_xor(sq, 8);
    sq += __shfl_xor(sq, 16); sq += __shfl_xor(sq, 32);
    float nv = val / fmaxf(sqrtf(sq), 1e-12f);
    if (emb_out) emb_out[base] = nv;
    res_out[base] = 0.5f * res_prev[base] + nv;
}

extern "C" void kernel_launch(void* const* d_in, const int* in_sizes, int n_in,
                              void* d_out, int out_size, void* d_ws, size_t ws_size,
                              hipStream_t stream) {
    const int*   edge_index = (const int*)d_in[0];   // [2, E]
    const int*   etype      = (const int*)d_in[1];   // [E]
    const float* ent        = (const float*)d_in[2]; // [N, 64]
    const float* rel        = (const float*)d_in[3]; // [R, 64]
    const float* W          = (const float*)d_in[4]; // [128, 64]

    const int E = in_sizes[1];
    const int N = in_sizes[2] / 64;
    const int R = in_sizes[3] / 64;
    const int* head = edge_index;
    const int* tail = edge_index + E;
    float* out = (float*)d_out;

    // workspace layout (16B-aligned chunks)
    char* w = (char*)d_ws;
    float* Wuv = (float*)w;        w += (size_t)R * 128 * 4;
    int* deg = (int*)w;            w += ((size_t)N + 8) * 4;
    int* rowstart = (int*)w;       w += ((size_t)N + 8) * 4;
    int* cursor = (int*)w;         w += ((size_t)N + 8) * 4;
    int* bsum = (int*)w;           w += 512 * 4;
    int* csr_tail = (int*)w;       w += (size_t)E * 4;
    int* csr_rtype = (int*)w;      w += (size_t)E * 4;
    float* emb1 = (float*)w;       w += (size_t)N * 64 * 4;

    const int nb = (N + 255) / 256;
    const int eb = (E + 255) / 256;
    const int hb = (N + 3) / 4;

    proj_kernel<<<R, 128, 0, stream>>>(W, rel, Wuv);

    // CSR build (graph constant across hops)
    hipMemsetAsync(deg, 0, (size_t)N * 4, stream);
    hist_kernel<<<eb, 256, 0, stream>>>(head, deg, E);
    block_sum_kernel<<<nb, 256, 0, stream>>>(deg, bsum, N);
    scan_bsum_kernel<<<1, 512, 0, stream>>>(bsum, nb);
    row_start_kernel<<<nb, 256, 0, stream>>>(deg, bsum, rowstart, cursor, N, E);
    fill_kernel<<<eb, 256, 0, stream>>>(head, tail, etype, cursor, csr_tail, csr_rtype, E);

    // hop 1: emb_in = ent, res = 0.5*ent + norm(hop(ent))
    hop_kernel<<<hb, 256, 0, stream>>>(rowstart, csr_tail, csr_rtype, Wuv,
                                       ent, ent, emb1, out, N);
    // hop 2: emb_in = emb1, res = 0.5*res + norm(hop(emb1)) (in place)
    hop_kernel<<<hb, 256, 0, stream>>>(rowstart, csr_tail, csr_rtype, Wuv,
                                       emb1, out, nullptr, out, N);
}

// Round 4
// 553.623 us; speedup vs baseline: 5.8553x; 1.9083x over previous
//
#include <hip/hip_runtime.h>

// ---------------------------------------------------------------------------
// RGAT 2-hop, N=100000, E=1600000, D=64, R=64.
// R4 = R3 + fix: all wave shuffles exec-unconditional (ds_bpermute from a
// masked-off lane is undefined; R3 read __shfl(hu,r) inside `if (lane<cnt)`).
// Logits via tables HU[n][r]=emb[n].u_r, TV[n][r]=emb[n].v_r (tiled GEMM per
// hop); per edge e = HU[h][r] + TV[t][r]; plain exp (|e| <~ 1.5, no max
// subtraction needed); weighted gather with 8 loads in flight.
// ---------------------------------------------------------------------------

#define NEG_SLOPE 0.2f

// Wuv[r*128 + i] = sum_j W[i][j] * rel[r][j],  i in [0,128)
__global__ void proj_kernel(const float* __restrict__ W,
                            const float* __restrict__ rel,
                            float* __restrict__ Wuv) {
    int r = blockIdx.x;
    int i = threadIdx.x;  // 0..127
    __shared__ float rels[64];
    if (i < 64) rels[i] = rel[r * 64 + i];
    __syncthreads();
    float s = 0.f;
#pragma unroll
    for (int j = 0; j < 64; ++j) s += W[i * 64 + j] * rels[j];
    Wuv[r * 128 + i] = s;
}

// ---------------- CSR build ----------------

__global__ __launch_bounds__(256) void hist_kernel(
    const int* __restrict__ head, int* __restrict__ deg, int E) {
    int i = blockIdx.x * 256 + threadIdx.x;
    if (i < E) atomicAdd(deg + head[i], 1);
}

__global__ __launch_bounds__(256) void block_sum_kernel(
    const int* __restrict__ deg, int* __restrict__ bsum, int N) {
    int i = blockIdx.x * 256 + threadIdx.x;
    int v = (i < N) ? deg[i] : 0;
#pragma unroll
    for (int m = 1; m < 64; m <<= 1) v += __shfl_xor(v, m);
    __shared__ int ws[4];
    if ((threadIdx.x & 63) == 0) ws[threadIdx.x >> 6] = v;
    __syncthreads();
    if (threadIdx.x == 0) bsum[blockIdx.x] = ws[0] + ws[1] + ws[2] + ws[3];
}

// single-block Hillis-Steele exclusive scan of bsum (nb <= 512)
__global__ __launch_bounds__(512) void scan_bsum_kernel(int* bsum, int nb) {
    __shared__ int s[512];
    int i = threadIdx.x;
    s[i] = (i < nb) ? bsum[i] : 0;
    __syncthreads();
    for (int off = 1; off < 512; off <<= 1) {
        int v = (i >= off) ? s[i - off] : 0;
        __syncthreads();
        s[i] += v;
        __syncthreads();
    }
    if (i < nb) bsum[i] = (i == 0) ? 0 : s[i - 1];
}

__global__ __launch_bounds__(256) void row_start_kernel(
    const int* __restrict__ deg, const int* __restrict__ bsum,
    int* __restrict__ rowstart, int* __restrict__ cursor, int N, int E) {
    int i = blockIdx.x * 256 + threadIdx.x;
    int v = (i < N) ? deg[i] : 0;
    int lane = threadIdx.x & 63;
    int wid = threadIdx.x >> 6;
    int sc = v;  // wave inclusive scan
#pragma unroll
    for (int off = 1; off < 64; off <<= 1) {
        int t = __shfl_up(sc, off);
        if (lane >= off) sc += t;
    }
    __shared__ int wsum[4];
    if (lane == 63) wsum[wid] = sc;
    __syncthreads();
    int wo = 0;
    for (int w = 0; w < wid; ++w) wo += wsum[w];
    int ex = sc - v + wo + bsum[blockIdx.x];
    if (i < N) { rowstart[i] = ex; cursor[i] = ex; }
    if (i == N - 1) rowstart[N] = E;
}

__global__ __launch_bounds__(256) void fill_kernel(
    const int* __restrict__ head, const int* __restrict__ tail,
    const int* __restrict__ etype, int* __restrict__ cursor,
    int* __restrict__ csr, int E) {
    int i = blockIdx.x * 256 + threadIdx.x;
    if (i >= E) return;
    int h = head[i];
    int pos = atomicAdd(cursor + h, 1);
    csr[pos] = (tail[i] << 6) | etype[i];   // t < 2^17, r < 64
}

// ---------------- HU/TV GEMM ----------------
// HU[n][r] = sum_d emb[n][d]*Wuv[r*128+d]; TV[n][r] = sum_d emb[n][d]*Wuv[r*128+64+d]
// Block = 256 thr computes 64-node x 128-col tile; thread = 4x8 micro-tile.
__global__ __launch_bounds__(256) void hu_tv_gemm(
    const float* __restrict__ emb, const float* __restrict__ Wuv,
    float* __restrict__ HU, float* __restrict__ TV, int N) {
    __shared__ float sA[64 * 68];   // sA[d*68+n] = emb[nbase+n][d] (transposed)
    __shared__ float sB[64 * 132];  // sB[d*132+c]: c<64 -> U_c[d], c>=64 -> V_{c-64}[d]
    int tid = threadIdx.x;
    long nbase = (long)blockIdx.x * 64;

    for (int i = tid; i < 64 * 128; i += 256) {
        int r = i >> 7, k = i & 127;
        float v = Wuv[i];
        int d = (k < 64) ? k : (k - 64);
        int c = (k < 64) ? r : (64 + r);
        sB[d * 132 + c] = v;
    }
    for (int i = tid; i < 64 * 16; i += 256) {
        int n = i >> 4, q = i & 15;
        long node = nbase + n;
        float4 v = (node < N) ? *(const float4*)(emb + node * 64 + q * 4)
                              : make_float4(0.f, 0.f, 0.f, 0.f);
        sA[(q * 4 + 0) * 68 + n] = v.x;
        sA[(q * 4 + 1) * 68 + n] = v.y;
        sA[(q * 4 + 2) * 68 + n] = v.z;
        sA[(q * 4 + 3) * 68 + n] = v.w;
    }
    __syncthreads();

    int wv = tid >> 6, lane = tid & 63;
    int g = lane & 15, cg = lane >> 4;
    int c0 = wv * 32 + cg * 8;       // wave cols are 32-aligned: all-HU or all-TV
    float acc[4][8] = {};
#pragma unroll 8
    for (int d = 0; d < 64; ++d) {
        const float4 a  = *(const float4*)&sA[d * 68 + g * 4];
        const float4 b0 = *(const float4*)&sB[d * 132 + c0];
        const float4 b1 = *(const float4*)&sB[d * 132 + c0 + 4];
        float av[4] = {a.x, a.y, a.z, a.w};
        float bv[8] = {b0.x, b0.y, b0.z, b0.w, b1.x, b1.y, b1.z, b1.w};
#pragma unroll
        for (int j = 0; j < 4; ++j)
#pragma unroll
            for (int c = 0; c < 8; ++c) acc[j][c] += av[j] * bv[c];
    }
    float* outp = (c0 < 64) ? HU : TV;
    int cc = c0 & 63;
#pragma unroll
    for (int j = 0; j < 4; ++j) {
        long node = nbase + g * 4 + j;
        if (node < N) {
            float4 o0 = {acc[j][0], acc[j][1], acc[j][2], acc[j][3]};
            float4 o1 = {acc[j][4], acc[j][5], acc[j][6], acc[j][7]};
            *(float4*)(outp + node * 64 + cc) = o0;
            *(float4*)(outp + node * 64 + cc + 4) = o1;
        }
    }
}

// ---------------- fused hop ----------------
// One wave per node, lane = dim. Phase A: 64 edge weights in parallel
// (lane = edge), ALL shuffles exec-unconditional. Phase B: weighted row
// gather, unrolled for MLP.
__global__ __launch_bounds__(256) void hop_kernel(
    const int* __restrict__ rowstart, const int* __restrict__ csr,
    const float* __restrict__ HU, const float* __restrict__ TV,
    const float* __restrict__ emb_in, const float* res_prev,
    float* emb_out, float* res_out, int N) {
    int node = blockIdx.x * 4 + (threadIdx.x >> 6);
    int lane = threadIdx.x & 63;
    if (node >= N) return;
    long base = (long)node * 64 + lane;
    float hd = emb_in[base];
    float hu = HU[base];                 // lane d holds HU[node][d]
    int s0 = rowstart[node], s1 = rowstart[node + 1];
    float agg = 0.f, lsum = 0.f;

    for (int s = s0; s < s1; s += 64) {
        int cnt = min(64, s1 - s);
        int pe = (lane < cnt) ? csr[s + lane] : 0;
        int t = pe >> 6, r = pe & 63;
        // ALL lanes active at the bpermute (fix for R3): pad lanes use
        // t=0,r=0 (valid addresses), weight forced to 0 below.
        float hur = __shfl(hu, r);
        float tv = TV[(long)t * 64 + r];
        float p = hur + tv;
        p = p > 0.f ? p : NEG_SLOPE * p;
        float w = (lane < cnt) ? __expf(p) : 0.f;
        lsum += w;                        // per-lane partial, reduced at end
#pragma unroll 8
        for (int i = 0; i < cnt; ++i) {
            float wi = __shfl(w, i);
            int ti = __shfl(t, i);
            agg += wi * emb_in[(long)ti * 64 + lane];
        }
    }
    // reduce lsum across lanes
    float l = lsum;
    l += __shfl_xor(l, 1);  l += __shfl_xor(l, 2);  l += __shfl_xor(l, 4);
    l += __shfl_xor(l, 8);  l += __shfl_xor(l, 16); l += __shfl_xor(l, 32);
    float val = hd;
    if (l > 0.f) val += agg / l;
    float sq = val * val;
    sq += __shfl_xor(sq, 1);  sq += __shfl_xor(sq, 2);  sq += __shfl_xor(sq, 4);
    sq += __shfl_xor(sq, 8);  sq += __shfl_xor(sq, 16); sq += __shfl_xor(sq, 32);
    float nv = val / fmaxf(sqrtf(sq), 1e-12f);
    if (emb_out) emb_out[base] = nv;
    res_out[base] = 0.5f * res_prev[base] + nv;
}

extern "C" void kernel_launch(void* const* d_in, const int* in_sizes, int n_in,
                              void* d_out, int out_size, void* d_ws, size_t ws_size,
                              hipStream_t stream) {
    const int*   edge_index = (const int*)d_in[0];   // [2, E]
    const int*   etype      = (const int*)d_in[1];   // [E]
    const float* ent        = (const float*)d_in[2]; // [N, 64]
    const float* rel        = (const float*)d_in[3]; // [R, 64]
    const float* W          = (const float*)d_in[4]; // [128, 64]

    const int E = in_sizes[1];
    const int N = in_sizes[2] / 64;
    const int R = in_sizes[3] / 64;
    const int* head = edge_index;
    const int* tail = edge_index + E;
    float* out = (float*)d_out;

    // workspace layout
    char* w = (char*)d_ws;
    float* Wuv = (float*)w;        w += (size_t)R * 128 * 4;
    int* deg = (int*)w;            w += ((size_t)N + 8) * 4;
    int* rowstart = (int*)w;       w += ((size_t)N + 8) * 4;
    int* cursor = (int*)w;         w += ((size_t)N + 8) * 4;
    int* bsum = (int*)w;           w += 512 * 4;
    int* csr = (int*)w;            w += (size_t)E * 4;
    float* HU = (float*)w;         w += (size_t)N * 64 * 4;
    float* TV = (float*)w;         w += (size_t)N * 64 * 4;
    float* emb1 = (float*)w;       w += (size_t)N * 64 * 4;

    const int nb = (N + 255) / 256;
    const int eb = (E + 255) / 256;
    const int hb = (N + 3) / 4;
    const int gb = (N + 63) / 64;

    proj_kernel<<<R, 128, 0, stream>>>(W, rel, Wuv);

    // CSR build (graph constant across hops)
    hipMemsetAsync(deg, 0, (size_t)N * 4, stream);
    hist_kernel<<<eb, 256, 0, stream>>>(head, deg, E);
    block_sum_kernel<<<nb, 256, 0, stream>>>(deg, bsum, N);
    scan_bsum_kernel<<<1, 512, 0, stream>>>(bsum, nb);
    row_start_kernel<<<nb, 256, 0, stream>>>(deg, bsum, rowstart, cursor, N, E);
    fill_kernel<<<eb, 256, 0, stream>>>(head, tail, etype, cursor, csr, E);

    // hop 1
    hu_tv_gemm<<<gb, 256, 0, stream>>>(ent, Wuv, HU, TV, N);
    hop_kernel<<<hb, 256, 0, stream>>>(rowstart, csr, HU, TV, ent, ent, emb1, out, N);
    // hop 2 (res in place)
    hu_tv_gemm<<<gb, 256, 0, stream>>>(emb1, Wuv, HU, TV, N);
    hop_kernel<<<hb, 256, 0, stream>>>(rowstart, csr, HU, TV, emb1, out, nullptr, out, N);
}